// Round 7
// baseline (595.061 us; speedup 1.0000x reference)
//
#include <hip/hip_runtime.h>

#define N_NODES 4194304
#define LEVELS  10
#define COARSE  8192
#define NNZ_E   8388608

typedef int          v4i __attribute__((ext_vector_type(4)));
typedef float        v4f __attribute__((ext_vector_type(4)));

static __device__ __forceinline__ unsigned short f2bf(float x) {
    unsigned u = __float_as_uint(x);
    return (unsigned short)((u + 0x7FFFu + ((u >> 16) & 1u)) >> 16);
}
static __device__ __forceinline__ float bf2f(unsigned short h) {
    return __uint_as_float((unsigned)h << 16);
}

// ============ k1: HODLR moments (+ init)
__global__ __launch_bounds__(512) void k1(const float* __restrict__ z,
                                          float2* __restrict__ M,
                                          float* __restrict__ S,
                                          float* __restrict__ out) {
    int b = blockIdx.x, t = threadIdx.x;
    if (b == 0) {
        for (int i = t; i < 2046 * 2; i += 512) S[i] = 0.f;
        if (t == 0) out[0] = 0.f;
    }
    int lane = t & 63, wave = t >> 6;
    int chunk = b * 8 + wave;
    int base = chunk * 256 + lane * 4;
    float4 zv = *(const float4*)(z + base);
    float a0 = 0.f, a1 = 0.f;
    const float* zp = (const float*)&zv;
#pragma unroll
    for (int j = 0; j < 4; ++j) {
        float p = ((float)(base + j) + 0.5f) * (1.0f / 512.0f) - 0.5f;
        p = fminf(fmaxf(p, 0.0f), (float)(COARSE - 1));
        float f = p - floorf(p);
        a0 += zp[j] * (1.0f - f);
        a1 += zp[j] * f;
    }
#pragma unroll
    for (int off = 32; off >= 1; off >>= 1) {
        a0 += __shfl_xor(a0, off, 64);
        a1 += __shfl_xor(a1, off, 64);
    }
    if (lane == 0) M[chunk] = make_float2(a0, a1);
}

// ============ kB: level sums
__global__ __launch_bounds__(256) void kB(const float2* __restrict__ M,
                                          const float* __restrict__ V,
                                          float* __restrict__ S) {
    int b = blockIdx.x, t = threadIdx.x;
    int lvl = b >> 3, slice = b & 7;
    const float2* Vl = (const float2*)(V + lvl * COARSE * 2);
    float s0 = 0.f, s1 = 0.f;
    int c0 = slice * 2048 + t * 8;
#pragma unroll
    for (int cc = 0; cc < 8; ++cc) {
        int c = c0 + cc;
        float2 m = M[c];
        int k = (c > 0) ? ((c - 1) >> 1) : 0;
        int kp = min(k + 1, COARSE - 1);
        float2 vk = Vl[k], vkp = Vl[kp];
        s0 += vk.x * m.x + vkp.x * m.y;
        s1 += vk.y * m.x + vkp.y * m.y;
    }
    int gw = min(1 << (10 - lvl), 64);
    for (int sh = gw >> 1; sh >= 1; sh >>= 1) {
        s0 += __shfl_xor(s0, sh, 64);
        s1 += __shfl_xor(s1, sh, 64);
    }
    if ((t & (gw - 1)) == 0) {
        int bb = c0 >> (13 - lvl);
        int soff = (2 << lvl) - 2;
        unsafeAtomicAdd(&S[(soff + bb) * 2 + 0], s0);
        unsafeAtomicAdd(&S[(soff + bb) * 2 + 1], s1);
    }
}

// ============ kCw: w = diag*z + lowrank -> bf16  (no LDS -> full occupancy)
__global__ __launch_bounds__(512) void kCw(const float* __restrict__ diag,
                                           const float* __restrict__ z,
                                           const float* __restrict__ S,
                                           const float* __restrict__ U,
                                           unsigned short* __restrict__ wb) {
    int b = blockIdx.x, t = threadIdx.x;
    int tid = b * 512 + t;
    int base = tid * 4;
    int c = base >> 8;                // wave-uniform chunk
    int k = (c > 0) ? ((c - 1) >> 1) : 0;
    int kp = min(k + 1, COARSE - 1);
    float g0 = 0.f, g1 = 0.f;
#pragma unroll
    for (int lvl = 0; lvl < LEVELS; ++lvl) {
        int sib = (c >> (13 - lvl)) ^ 1;
        int soff = (2 << lvl) - 2;
        float2 s2 = ((const float2*)S)[soff + sib];
        const float2* Ul = (const float2*)(U + lvl * COARSE * 2);
        float2 uk = Ul[k], ukp = Ul[kp];
        g0 += uk.x * s2.x + uk.y * s2.y;
        g1 += ukp.x * s2.x + ukp.y * s2.y;
    }
    float4 d4 = *(const float4*)(diag + base);
    float4 z4 = *(const float4*)(z + base);
    const float* dp = (const float*)&d4;
    const float* zp = (const float*)&z4;
    ushort4 h4;
    unsigned short* hp = (unsigned short*)&h4;
#pragma unroll
    for (int j = 0; j < 4; ++j) {
        float p = ((float)(base + j) + 0.5f) * (1.0f / 512.0f) - 0.5f;
        p = fminf(fmaxf(p, 0.0f), (float)(COARSE - 1));
        float f = p - floorf(p);
        hp[j] = f2bf(dp[j] * zp[j] + (g0 + f * (g1 - g0)));
    }
    *(ushort4*)(wb + base) = h4;
}

// ============ k2: zero-sort SpMV — stream edges, gather wb[col], fp32 product,
// device-scope atomicAdd into global y. 4 col-phases (2 MiB wb window ~ half of
// per-XCD L2) with block barrier to keep co-resident blocks phase-aligned.
// No LDS -> 3+ blocks/CU; atomics are fire-and-forget (hidden under gathers).
__global__ __launch_bounds__(512) void k2(const int* __restrict__ rows,
                                          const int* __restrict__ cols,
                                          const float* __restrict__ vals,
                                          const unsigned short* __restrict__ wb,
                                          float* __restrict__ y) {
    int blk = blockIdx.x, t = threadIdx.x;
    int base = blk * 4096;
    v4i r[2], c[2];
    v4f v[2];
#pragma unroll
    for (int j = 0; j < 2; ++j) {
        int e = base + j * 2048 + t * 4;
        r[j] = __builtin_nontemporal_load((const v4i*)(rows + e));
        c[j] = __builtin_nontemporal_load((const v4i*)(cols + e));
        v[j] = __builtin_nontemporal_load((const v4f*)(vals + e));
    }
#pragma unroll 1
    for (int p = 0; p < 4; ++p) {
#pragma unroll
        for (int j = 0; j < 2; ++j) {
            const int* rp = (const int*)&r[j];
            const int* cp = (const int*)&c[j];
            const float* vp = (const float*)&v[j];
#pragma unroll
            for (int kk = 0; kk < 4; ++kk) {
                unsigned cc = (unsigned)cp[kk];
                if ((cc >> 20) == (unsigned)p) {
                    float w = bf2f(wb[cc]);
                    unsafeAtomicAdd(&y[(unsigned)rp[kk]], vp[kk] * w);
                }
            }
        }
        __syncthreads();
    }
}

// ============ kL: fused loss = mean((y - z)^2)
__global__ __launch_bounds__(512) void kL(const float* __restrict__ y,
                                          const float* __restrict__ z,
                                          float* __restrict__ out) {
    __shared__ float red[8];
    int b = blockIdx.x, t = threadIdx.x;
    int base = (b * 512 + t) * 4;
    float4 y4 = *(const float4*)(y + base);
    float4 z4 = *(const float4*)(z + base);
    float d0 = y4.x - z4.x, d1 = y4.y - z4.y, d2 = y4.z - z4.z, d3 = y4.w - z4.w;
    float part = d0 * d0 + d1 * d1 + d2 * d2 + d3 * d3;
#pragma unroll
    for (int off = 32; off >= 1; off >>= 1) part += __shfl_xor(part, off, 64);
    if ((t & 63) == 0) red[t >> 6] = part;
    __syncthreads();
    if (t == 0) {
        float s = 0.f;
        for (int i = 0; i < 8; ++i) s += red[i];
        unsafeAtomicAdd(out, s * (1.0f / (float)N_NODES));
    }
}

extern "C" void kernel_launch(void* const* d_in, const int* in_sizes, int n_in,
                              void* d_out, int out_size, void* d_ws, size_t ws_size,
                              hipStream_t stream) {
    const float* diag  = (const float*)d_in[0];
    const float* U     = (const float*)d_in[1];
    const float* V     = (const float*)d_in[2];
    const float* Avals = (const float*)d_in[3];
    const float* z     = (const float*)d_in[4];
    const int*   Aidx  = (const int*)d_in[5];
    const int* rows = Aidx;
    const int* cols = Aidx + NNZ_E;

    char* ws = (char*)d_ws;
    size_t off = 0;
    unsigned short* wb  = (unsigned short*)(ws + off); off += (size_t)N_NODES * 2;         // 8 MiB
    float* y            = (float*)(ws + off);          off += (size_t)N_NODES * 4;         // 16 MiB
    float2* M           = (float2*)(ws + off);         off += (size_t)(N_NODES / 256) * 8; // 128 KiB
    float* S            = (float*)(ws + off);          off += 16384;

    hipMemsetAsync(y, 0, (size_t)N_NODES * 4, stream);
    k1<<<2048, 512, 0, stream>>>(z, M, S, (float*)d_out);
    kB<<<80, 256, 0, stream>>>(M, V, S);
    kCw<<<2048, 512, 0, stream>>>(diag, z, S, U, wb);
    k2<<<2048, 512, 0, stream>>>(rows, cols, Avals, wb, y);
    kL<<<2048, 512, 0, stream>>>(y, z, (float*)d_out);
}

// Round 8
// 302.622 us; speedup vs baseline: 1.9663x; 1.9663x over previous
//
#include <hip/hip_runtime.h>

#define N_NODES 4194304
#define LEVELS  10
#define COARSE  8192
#define NNZ_E   8388608
#define NSEG    512      // row segments (8192 rows each)
#define RB_SZ   8192     // rows per kE block (32 KiB LDS accumulator)
#define EPB     8192     // edges per bin+product block
#define CAP_SEG 18432u   // per-segment capacity: mean 16384, +16 sigma

typedef int          v4i __attribute__((ext_vector_type(4)));
typedef float        v4f __attribute__((ext_vector_type(4)));
typedef unsigned int v4u __attribute__((ext_vector_type(4)));

static __device__ __forceinline__ unsigned short f2bf(float x) {
    unsigned u = __float_as_uint(x);
    return (unsigned short)((u + 0x7FFFu + ((u >> 16) & 1u)) >> 16);
}
static __device__ __forceinline__ float bf2f(unsigned short h) {
    return __uint_as_float((unsigned)h << 16);
}

// ============ k1: HODLR moments (+ init)
__global__ __launch_bounds__(512) void k1(const float* __restrict__ z,
                                          float2* __restrict__ M,
                                          float* __restrict__ S,
                                          float* __restrict__ out) {
    int b = blockIdx.x, t = threadIdx.x;
    if (b == 0) {
        for (int i = t; i < 2046 * 2; i += 512) S[i] = 0.f;
        if (t == 0) out[0] = 0.f;
    }
    int lane = t & 63, wave = t >> 6;
    int chunk = b * 8 + wave;
    int base = chunk * 256 + lane * 4;
    float4 zv = *(const float4*)(z + base);
    float a0 = 0.f, a1 = 0.f;
    const float* zp = (const float*)&zv;
#pragma unroll
    for (int j = 0; j < 4; ++j) {
        float p = ((float)(base + j) + 0.5f) * (1.0f / 512.0f) - 0.5f;
        p = fminf(fmaxf(p, 0.0f), (float)(COARSE - 1));
        float f = p - floorf(p);
        a0 += zp[j] * (1.0f - f);
        a1 += zp[j] * f;
    }
#pragma unroll
    for (int off = 32; off >= 1; off >>= 1) {
        a0 += __shfl_xor(a0, off, 64);
        a1 += __shfl_xor(a1, off, 64);
    }
    if (lane == 0) M[chunk] = make_float2(a0, a1);
}

// ============ kB: level sums
__global__ __launch_bounds__(256) void kB(const float2* __restrict__ M,
                                          const float* __restrict__ V,
                                          float* __restrict__ S) {
    int b = blockIdx.x, t = threadIdx.x;
    int lvl = b >> 3, slice = b & 7;
    const float2* Vl = (const float2*)(V + lvl * COARSE * 2);
    float s0 = 0.f, s1 = 0.f;
    int c0 = slice * 2048 + t * 8;
#pragma unroll
    for (int cc = 0; cc < 8; ++cc) {
        int c = c0 + cc;
        float2 m = M[c];
        int k = (c > 0) ? ((c - 1) >> 1) : 0;
        int kp = min(k + 1, COARSE - 1);
        float2 vk = Vl[k], vkp = Vl[kp];
        s0 += vk.x * m.x + vkp.x * m.y;
        s1 += vk.y * m.x + vkp.y * m.y;
    }
    int gw = min(1 << (10 - lvl), 64);
    for (int sh = gw >> 1; sh >= 1; sh >>= 1) {
        s0 += __shfl_xor(s0, sh, 64);
        s1 += __shfl_xor(s1, sh, 64);
    }
    if ((t & (gw - 1)) == 0) {
        int bb = c0 >> (13 - lvl);
        int soff = (2 << lvl) - 2;
        unsafeAtomicAdd(&S[(soff + bb) * 2 + 0], s0);
        unsafeAtomicAdd(&S[(soff + bb) * 2 + 1], s1);
    }
}

// ============ kCw: w = diag*z + lowrank -> bf16  (no LDS -> full occupancy)
__global__ __launch_bounds__(512) void kCw(const float* __restrict__ diag,
                                           const float* __restrict__ z,
                                           const float* __restrict__ S,
                                           const float* __restrict__ U,
                                           unsigned short* __restrict__ wb) {
    int b = blockIdx.x, t = threadIdx.x;
    int tid = b * 512 + t;
    int base = tid * 4;
    int c = base >> 8;                // wave-uniform chunk
    int k = (c > 0) ? ((c - 1) >> 1) : 0;
    int kp = min(k + 1, COARSE - 1);
    float g0 = 0.f, g1 = 0.f;
#pragma unroll
    for (int lvl = 0; lvl < LEVELS; ++lvl) {
        int sib = (c >> (13 - lvl)) ^ 1;
        int soff = (2 << lvl) - 2;
        float2 s2 = ((const float2*)S)[soff + sib];
        const float2* Ul = (const float2*)(U + lvl * COARSE * 2);
        float2 uk = Ul[k], ukp = Ul[kp];
        g0 += uk.x * s2.x + uk.y * s2.y;
        g1 += ukp.x * s2.x + ukp.y * s2.y;
    }
    float4 d4 = *(const float4*)(diag + base);
    float4 z4 = *(const float4*)(z + base);
    const float* dp = (const float*)&d4;
    const float* zp = (const float*)&z4;
    ushort4 h4;
    unsigned short* hp = (unsigned short*)&h4;
#pragma unroll
    for (int j = 0; j < 4; ++j) {
        float p = ((float)(base + j) + 0.5f) * (1.0f / 512.0f) - 0.5f;
        p = fminf(fmaxf(p, 0.0f), (float)(COARSE - 1));
        float f = p - floorf(p);
        hp[j] = f2bf(dp[j] * zp[j] + (g0 + f * (g1 - g0)));
    }
    *(ushort4*)(wb + base) = h4;
}

// ============ k2: bin + product fused, COL-PHASED gather (runs after kCw).
// Edges held in registers; wb[col] gathered in 4 phases of 1M cols (2 MiB wb
// window = half per-XCD L2), block barrier between phases (vmcnt drain enforces
// window discipline; 2 blocks/CU cover the stall). Then product + 4-byte
// row-segment binning exactly as round 6.
__global__ __launch_bounds__(1024) void k2(const int* __restrict__ rows,
                                           const int* __restrict__ cols,
                                           const float* __restrict__ vals,
                                           const unsigned short* __restrict__ wb,
                                           unsigned* __restrict__ segCtr,
                                           unsigned* __restrict__ binned) {
    __shared__ unsigned sortedP[EPB];        // 32 KiB
    __shared__ unsigned short sortedB[EPB];  // 16 KiB
    __shared__ unsigned cur[NSEG], gb[NSEG]; // 4 KiB
    __shared__ unsigned wsum[16], wbase[16];
    int blk = blockIdx.x, t = threadIdx.x;
    int base = blk * EPB;
    // streaming loads upfront (MLP)
    v4i r[2], c[2];
    v4f v[2];
#pragma unroll
    for (int j = 0; j < 2; ++j) {
        int e = base + j * 4096 + t * 4;
        r[j] = __builtin_nontemporal_load((const v4i*)(rows + e));
        c[j] = __builtin_nontemporal_load((const v4i*)(cols + e));
        v[j] = __builtin_nontemporal_load((const v4f*)(vals + e));
    }
    // phased gather: 2 MiB wb window per phase
    float wf[8];
#pragma unroll 1
    for (int p = 0; p < 4; ++p) {
#pragma unroll
        for (int j = 0; j < 2; ++j) {
            const int* cp = (const int*)&c[j];
#pragma unroll
            for (int kk = 0; kk < 4; ++kk) {
                unsigned cc = (unsigned)cp[kk];
                if ((cc >> 20) == (unsigned)p)
                    wf[j * 4 + kk] = bf2f(wb[cc]);
            }
        }
        __syncthreads();
    }
    if (t < NSEG) cur[t] = 0u;
    __syncthreads();
    // histogram by row segment
#pragma unroll
    for (int j = 0; j < 2; ++j) {
        const int* rp = (const int*)&r[j];
#pragma unroll
        for (int kk = 0; kk < 4; ++kk)
            atomicAdd(&cur[(unsigned)rp[kk] >> 13], 1u);
    }
    __syncthreads();
    // scan 512 counters with first 8 waves (wave-uniform branch)
    unsigned lv = 0, lincl = 0;
    if (t < NSEG) {
        lv = cur[t];
        lincl = lv;
#pragma unroll
        for (int off = 1; off < 64; off <<= 1) {
            unsigned n = __shfl_up(lincl, off, 64);
            if ((t & 63) >= off) lincl += n;
        }
        if ((t & 63) == 63) wsum[t >> 6] = lincl;
    }
    __syncthreads();
    if (t == 0) {
        unsigned a = 0;
        for (int i = 0; i < 8; ++i) { wbase[i] = a; a += wsum[i]; }
    }
    __syncthreads();
    if (t < NSEG) {
        unsigned lexcl = wbase[t >> 6] + lincl - lv;
        gb[t] = (unsigned)t * CAP_SEG + atomicAdd(&segCtr[t], lv) - lexcl;
        cur[t] = lexcl;
    }
    __syncthreads();
    // product + scatter into LDS, sorted by segment
#pragma unroll
    for (int j = 0; j < 2; ++j) {
        const int* rp = (const int*)&r[j];
        const float* vp = (const float*)&v[j];
#pragma unroll
        for (int kk = 0; kk < 4; ++kk) {
            unsigned row = (unsigned)rp[kk];
            unsigned seg = row >> 13;
            unsigned rl = row & 8191u;
            float p = wf[j * 4 + kk] * vp[kk];
            unsigned pe = ((__float_as_uint(p) + 0x1000u) >> 13) & 0x7FFFFu;
            unsigned i = atomicAdd(&cur[seg], 1u);
            sortedP[i] = (rl << 19) | pe;
            sortedB[i] = (unsigned short)seg;
        }
    }
    __syncthreads();
    // coalesced write-out (16-entry avg runs, 64 B)
#pragma unroll
    for (int k = 0; k < 8; ++k) {
        int i = k * 1024 + t;
        unsigned s = sortedB[i];
        __builtin_nontemporal_store(sortedP[i], binned + gb[s] + i);
    }
}

// ============ kE: pure streaming accumulate + fused loss (no gather).
// 512 blocks x 1024 thr, 32 KiB acc -> 2 blocks/CU.
__global__ __launch_bounds__(1024) void kE(const unsigned* __restrict__ binned,
                                           const unsigned* __restrict__ segCtr,
                                           const float* __restrict__ z,
                                           float* __restrict__ out) {
    __shared__ float acc[RB_SZ];          // 32 KiB
    __shared__ float red[16];
    int b = blockIdx.x, t = threadIdx.x;

    for (int i = t; i < RB_SZ / 4; i += 1024) ((float4*)acc)[i] = make_float4(0.f, 0.f, 0.f, 0.f);
    __syncthreads();

    unsigned n = segCtr[b];
    const unsigned* seg = binned + (size_t)b * CAP_SEG;
    unsigned i = t;
    for (; i + 7u * 1024u < n; i += 8u * 1024u) {
        unsigned ev[8];
#pragma unroll
        for (int k = 0; k < 8; ++k)
            ev[k] = __builtin_nontemporal_load(seg + i + (unsigned)k * 1024u);
#pragma unroll
        for (int k = 0; k < 8; ++k)
            atomicAdd(&acc[ev[k] >> 19], __uint_as_float((ev[k] & 0x7FFFFu) << 13));
    }
    for (; i < n; i += 1024u) {
        unsigned e = __builtin_nontemporal_load(seg + i);
        atomicAdd(&acc[e >> 19], __uint_as_float((e & 0x7FFFFu) << 13));
    }
    __syncthreads();

    float part = 0.f;
    int gbase = b * RB_SZ;
    for (int k = t; k < RB_SZ; k += 1024) {
        float d = acc[k] - z[gbase + k];
        part += d * d;
    }
#pragma unroll
    for (int off = 32; off >= 1; off >>= 1) part += __shfl_xor(part, off, 64);
    if ((t & 63) == 0) red[t >> 6] = part;
    __syncthreads();
    if (t == 0) {
        float s = 0.f;
        for (int k = 0; k < 16; ++k) s += red[k];
        unsafeAtomicAdd(out, s * (1.0f / (float)N_NODES));
    }
}

extern "C" void kernel_launch(void* const* d_in, const int* in_sizes, int n_in,
                              void* d_out, int out_size, void* d_ws, size_t ws_size,
                              hipStream_t stream) {
    const float* diag  = (const float*)d_in[0];
    const float* U     = (const float*)d_in[1];
    const float* V     = (const float*)d_in[2];
    const float* Avals = (const float*)d_in[3];
    const float* z     = (const float*)d_in[4];
    const int*   Aidx  = (const int*)d_in[5];
    const int* rows = Aidx;
    const int* cols = Aidx + NNZ_E;

    char* ws = (char*)d_ws;
    size_t off = 0;
    unsigned short* wb  = (unsigned short*)(ws + off); off += (size_t)N_NODES * 2;          // 8 MiB
    unsigned* binned    = (unsigned*)(ws + off);       off += (size_t)NSEG * CAP_SEG * 4;   // 37.75 MiB
    unsigned* segCtr    = (unsigned*)(ws + off);       off += NSEG * 4;
    float2* M           = (float2*)(ws + off);         off += (size_t)(N_NODES / 256) * 8;  // 128 KiB
    float* S            = (float*)(ws + off);          off += 16384;

    hipMemsetAsync(segCtr, 0, NSEG * 4, stream);
    k1<<<2048, 512, 0, stream>>>(z, M, S, (float*)d_out);
    kB<<<80, 256, 0, stream>>>(M, V, S);
    kCw<<<2048, 512, 0, stream>>>(diag, z, S, U, wb);
    k2<<<1024, 1024, 0, stream>>>(rows, cols, Avals, wb, segCtr, binned);
    kE<<<NSEG, 1024, 0, stream>>>(binned, segCtr, z, (float*)d_out);
}

// Round 9
// 301.949 us; speedup vs baseline: 1.9707x; 1.0022x over previous
//
#include <hip/hip_runtime.h>

#define N_NODES 4194304
#define LEVELS  10
#define COARSE  8192
#define NNZ_E   8388608
#define NSEG    512      // row segments (8192 rows each)
#define RB_SZ   8192     // rows per kE block (32 KiB LDS accumulator)
#define EPB     8192     // edges per bin+product block
#define CAP_SEG 18432u   // per-segment capacity: mean 16384, +16 sigma

typedef int          v4i __attribute__((ext_vector_type(4)));
typedef float        v4f __attribute__((ext_vector_type(4)));
typedef unsigned int v4u __attribute__((ext_vector_type(4)));

static __device__ __forceinline__ unsigned short f2bf(float x) {
    unsigned u = __float_as_uint(x);
    return (unsigned short)((u + 0x7FFFu + ((u >> 16) & 1u)) >> 16);
}
static __device__ __forceinline__ float bf2f(unsigned short h) {
    return __uint_as_float((unsigned)h << 16);
}

// ============ k1: HODLR moments (+ init of S, out, segCtr — memset dispatch folded in)
__global__ __launch_bounds__(512) void k1(const float* __restrict__ z,
                                          float2* __restrict__ M,
                                          float* __restrict__ S,
                                          float* __restrict__ out,
                                          unsigned* __restrict__ segCtr) {
    int b = blockIdx.x, t = threadIdx.x;
    if (b == 0) {
        for (int i = t; i < 2046 * 2; i += 512) S[i] = 0.f;
        if (t == 0) out[0] = 0.f;
        segCtr[t] = 0u;   // t in [0,512) covers NSEG
    }
    int lane = t & 63, wave = t >> 6;
    int chunk = b * 8 + wave;
    int base = chunk * 256 + lane * 4;
    float4 zv = *(const float4*)(z + base);
    float a0 = 0.f, a1 = 0.f;
    const float* zp = (const float*)&zv;
#pragma unroll
    for (int j = 0; j < 4; ++j) {
        float p = ((float)(base + j) + 0.5f) * (1.0f / 512.0f) - 0.5f;
        p = fminf(fmaxf(p, 0.0f), (float)(COARSE - 1));
        float f = p - floorf(p);
        a0 += zp[j] * (1.0f - f);
        a1 += zp[j] * f;
    }
#pragma unroll
    for (int off = 32; off >= 1; off >>= 1) {
        a0 += __shfl_xor(a0, off, 64);
        a1 += __shfl_xor(a1, off, 64);
    }
    if (lane == 0) M[chunk] = make_float2(a0, a1);
}

// ============ kB: level sums
__global__ __launch_bounds__(256) void kB(const float2* __restrict__ M,
                                          const float* __restrict__ V,
                                          float* __restrict__ S) {
    int b = blockIdx.x, t = threadIdx.x;
    int lvl = b >> 3, slice = b & 7;
    const float2* Vl = (const float2*)(V + lvl * COARSE * 2);
    float s0 = 0.f, s1 = 0.f;
    int c0 = slice * 2048 + t * 8;
#pragma unroll
    for (int cc = 0; cc < 8; ++cc) {
        int c = c0 + cc;
        float2 m = M[c];
        int k = (c > 0) ? ((c - 1) >> 1) : 0;
        int kp = min(k + 1, COARSE - 1);
        float2 vk = Vl[k], vkp = Vl[kp];
        s0 += vk.x * m.x + vkp.x * m.y;
        s1 += vk.y * m.x + vkp.y * m.y;
    }
    int gw = min(1 << (10 - lvl), 64);
    for (int sh = gw >> 1; sh >= 1; sh >>= 1) {
        s0 += __shfl_xor(s0, sh, 64);
        s1 += __shfl_xor(s1, sh, 64);
    }
    if ((t & (gw - 1)) == 0) {
        int bb = c0 >> (13 - lvl);
        int soff = (2 << lvl) - 2;
        unsafeAtomicAdd(&S[(soff + bb) * 2 + 0], s0);
        unsafeAtomicAdd(&S[(soff + bb) * 2 + 1], s1);
    }
}

// ============ kCw: w = diag*z + lowrank -> bf16  (no LDS -> full occupancy)
__global__ __launch_bounds__(512) void kCw(const float* __restrict__ diag,
                                           const float* __restrict__ z,
                                           const float* __restrict__ S,
                                           const float* __restrict__ U,
                                           unsigned short* __restrict__ wb) {
    int b = blockIdx.x, t = threadIdx.x;
    int tid = b * 512 + t;
    int base = tid * 4;
    int c = base >> 8;                // wave-uniform chunk
    int k = (c > 0) ? ((c - 1) >> 1) : 0;
    int kp = min(k + 1, COARSE - 1);
    float g0 = 0.f, g1 = 0.f;
#pragma unroll
    for (int lvl = 0; lvl < LEVELS; ++lvl) {
        int sib = (c >> (13 - lvl)) ^ 1;
        int soff = (2 << lvl) - 2;
        float2 s2 = ((const float2*)S)[soff + sib];
        const float2* Ul = (const float2*)(U + lvl * COARSE * 2);
        float2 uk = Ul[k], ukp = Ul[kp];
        g0 += uk.x * s2.x + uk.y * s2.y;
        g1 += ukp.x * s2.x + ukp.y * s2.y;
    }
    float4 d4 = *(const float4*)(diag + base);
    float4 z4 = *(const float4*)(z + base);
    const float* dp = (const float*)&d4;
    const float* zp = (const float*)&z4;
    ushort4 h4;
    unsigned short* hp = (unsigned short*)&h4;
#pragma unroll
    for (int j = 0; j < 4; ++j) {
        float p = ((float)(base + j) + 0.5f) * (1.0f / 512.0f) - 0.5f;
        p = fminf(fmaxf(p, 0.0f), (float)(COARSE - 1));
        float f = p - floorf(p);
        hp[j] = f2bf(dp[j] * zp[j] + (g0 + f * (g1 - g0)));
    }
    *(ushort4*)(wb + base) = h4;
}

// ============ k2: bin + product fused, col-phased gather with PER-WAVE drains.
// Each phase: issue masked gathers (2 MiB wb window) + 2/8 of the row-histogram
// (LDS work under gather latency), then s_waitcnt vmcnt(0) per wave (no block
// barrier, no lgkm drain) — preserves issue-order col windows while waves stay
// independent. Then scan/reserve/scatter/write-out as round 8.
template<int P, int S0, int S1>
static __device__ __forceinline__ void gphase(const v4i* r, const v4i* c,
                                              const unsigned short* __restrict__ wb,
                                              float* wf, unsigned* cur) {
#pragma unroll
    for (int j = 0; j < 2; ++j) {
        const int* cp = (const int*)&c[j];
#pragma unroll
        for (int kk = 0; kk < 4; ++kk) {
            unsigned cc = (unsigned)cp[kk];
            if ((cc >> 20) == (unsigned)P)
                wf[j * 4 + kk] = bf2f(wb[cc]);
        }
    }
    {
        unsigned rr = (unsigned)((const int*)&r[S0 >> 2])[S0 & 3];
        atomicAdd(&cur[rr >> 13], 1u);
    }
    {
        unsigned rr = (unsigned)((const int*)&r[S1 >> 2])[S1 & 3];
        atomicAdd(&cur[rr >> 13], 1u);
    }
    asm volatile("s_waitcnt vmcnt(0)" ::: "memory");
    __builtin_amdgcn_sched_barrier(0);
}

__global__ __launch_bounds__(1024) void k2(const int* __restrict__ rows,
                                           const int* __restrict__ cols,
                                           const float* __restrict__ vals,
                                           const unsigned short* __restrict__ wb,
                                           unsigned* __restrict__ segCtr,
                                           unsigned* __restrict__ binned) {
    __shared__ unsigned sortedP[EPB];        // 32 KiB
    __shared__ unsigned short sortedB[EPB];  // 16 KiB
    __shared__ unsigned cur[NSEG], gb[NSEG]; // 4 KiB
    __shared__ unsigned wsum[16], wbase[16];
    int blk = blockIdx.x, t = threadIdx.x;
    int base = blk * EPB;
    // streaming loads upfront (MLP)
    v4i r[2], c[2];
    v4f v[2];
#pragma unroll
    for (int j = 0; j < 2; ++j) {
        int e = base + j * 4096 + t * 4;
        r[j] = __builtin_nontemporal_load((const v4i*)(rows + e));
        c[j] = __builtin_nontemporal_load((const v4i*)(cols + e));
        v[j] = __builtin_nontemporal_load((const v4f*)(vals + e));
    }
    if (t < NSEG) cur[t] = 0u;
    __syncthreads();
    // phased gather + interleaved histogram; per-wave vmcnt drains only
    float wf[8];
    gphase<0, 0, 1>(r, c, wb, wf, cur);
    gphase<1, 2, 3>(r, c, wb, wf, cur);
    gphase<2, 4, 5>(r, c, wb, wf, cur);
    gphase<3, 6, 7>(r, c, wb, wf, cur);
    __syncthreads();   // completes hist (lgkm); vmcnt already drained per wave
    // scan 512 counters with first 8 waves (wave-uniform branch)
    unsigned lv = 0, lincl = 0;
    if (t < NSEG) {
        lv = cur[t];
        lincl = lv;
#pragma unroll
        for (int off = 1; off < 64; off <<= 1) {
            unsigned n = __shfl_up(lincl, off, 64);
            if ((t & 63) >= off) lincl += n;
        }
        if ((t & 63) == 63) wsum[t >> 6] = lincl;
    }
    __syncthreads();
    if (t == 0) {
        unsigned a = 0;
        for (int i = 0; i < 8; ++i) { wbase[i] = a; a += wsum[i]; }
    }
    __syncthreads();
    if (t < NSEG) {
        unsigned lexcl = wbase[t >> 6] + lincl - lv;
        gb[t] = (unsigned)t * CAP_SEG + atomicAdd(&segCtr[t], lv) - lexcl;
        cur[t] = lexcl;
    }
    __syncthreads();
    // product + scatter into LDS, sorted by segment
#pragma unroll
    for (int j = 0; j < 2; ++j) {
        const int* rp = (const int*)&r[j];
        const float* vp = (const float*)&v[j];
#pragma unroll
        for (int kk = 0; kk < 4; ++kk) {
            unsigned row = (unsigned)rp[kk];
            unsigned seg = row >> 13;
            unsigned rl = row & 8191u;
            float p = wf[j * 4 + kk] * vp[kk];
            unsigned pe = ((__float_as_uint(p) + 0x1000u) >> 13) & 0x7FFFFu;
            unsigned i = atomicAdd(&cur[seg], 1u);
            sortedP[i] = (rl << 19) | pe;
            sortedB[i] = (unsigned short)seg;
        }
    }
    __syncthreads();
    // coalesced write-out (16-entry avg runs, 64 B)
#pragma unroll
    for (int k = 0; k < 8; ++k) {
        int i = k * 1024 + t;
        unsigned s = sortedB[i];
        __builtin_nontemporal_store(sortedP[i], binned + gb[s] + i);
    }
}

// ============ kE: pure streaming accumulate + fused loss (no gather).
// 512 blocks x 1024 thr, 32 KiB acc -> 2 blocks/CU.
__global__ __launch_bounds__(1024) void kE(const unsigned* __restrict__ binned,
                                           const unsigned* __restrict__ segCtr,
                                           const float* __restrict__ z,
                                           float* __restrict__ out) {
    __shared__ float acc[RB_SZ];          // 32 KiB
    __shared__ float red[16];
    int b = blockIdx.x, t = threadIdx.x;

    for (int i = t; i < RB_SZ / 4; i += 1024) ((float4*)acc)[i] = make_float4(0.f, 0.f, 0.f, 0.f);
    __syncthreads();

    unsigned n = segCtr[b];
    const unsigned* seg = binned + (size_t)b * CAP_SEG;
    unsigned i = t;
    for (; i + 7u * 1024u < n; i += 8u * 1024u) {
        unsigned ev[8];
#pragma unroll
        for (int k = 0; k < 8; ++k)
            ev[k] = __builtin_nontemporal_load(seg + i + (unsigned)k * 1024u);
#pragma unroll
        for (int k = 0; k < 8; ++k)
            atomicAdd(&acc[ev[k] >> 19], __uint_as_float((ev[k] & 0x7FFFFu) << 13));
    }
    for (; i < n; i += 1024u) {
        unsigned e = __builtin_nontemporal_load(seg + i);
        atomicAdd(&acc[e >> 19], __uint_as_float((e & 0x7FFFFu) << 13));
    }
    __syncthreads();

    float part = 0.f;
    int gbase = b * RB_SZ;
    for (int k = t; k < RB_SZ; k += 1024) {
        float d = acc[k] - z[gbase + k];
        part += d * d;
    }
#pragma unroll
    for (int off = 32; off >= 1; off >>= 1) part += __shfl_xor(part, off, 64);
    if ((t & 63) == 0) red[t >> 6] = part;
    __syncthreads();
    if (t == 0) {
        float s = 0.f;
        for (int k = 0; k < 16; ++k) s += red[k];
        unsafeAtomicAdd(out, s * (1.0f / (float)N_NODES));
    }
}

extern "C" void kernel_launch(void* const* d_in, const int* in_sizes, int n_in,
                              void* d_out, int out_size, void* d_ws, size_t ws_size,
                              hipStream_t stream) {
    const float* diag  = (const float*)d_in[0];
    const float* U     = (const float*)d_in[1];
    const float* V     = (const float*)d_in[2];
    const float* Avals = (const float*)d_in[3];
    const float* z     = (const float*)d_in[4];
    const int*   Aidx  = (const int*)d_in[5];
    const int* rows = Aidx;
    const int* cols = Aidx + NNZ_E;

    char* ws = (char*)d_ws;
    size_t off = 0;
    unsigned short* wb  = (unsigned short*)(ws + off); off += (size_t)N_NODES * 2;          // 8 MiB
    unsigned* binned    = (unsigned*)(ws + off);       off += (size_t)NSEG * CAP_SEG * 4;   // 37.75 MiB
    unsigned* segCtr    = (unsigned*)(ws + off);       off += NSEG * 4;
    float2* M           = (float2*)(ws + off);         off += (size_t)(N_NODES / 256) * 8;  // 128 KiB
    float* S            = (float*)(ws + off);          off += 16384;

    k1<<<2048, 512, 0, stream>>>(z, M, S, (float*)d_out, segCtr);
    kB<<<80, 256, 0, stream>>>(M, V, S);
    kCw<<<2048, 512, 0, stream>>>(diag, z, S, U, wb);
    k2<<<1024, 1024, 0, stream>>>(rows, cols, Avals, wb, segCtr, binned);
    kE<<<NSEG, 1024, 0, stream>>>(binned, segCtr, z, (float*)d_out);
}